// Round 14
// baseline (483.507 us; speedup 1.0000x reference)
//
#include <hip/hip_runtime.h>
#include <hip/hip_bf16.h>
#include <math.h>

#define D_MODEL 2048
#define N_HEADS 16
#define D_HEAD  128
#define BATCH   64
#define SEQ     128
#define BT      (BATCH*SEQ)   // 8192 rows
#define LDF     6144          // fused QKV row stride
#define KOFF    2048
#define VOFF    4096

typedef __bf16 bf16;
typedef __attribute__((ext_vector_type(8))) __bf16 bf16x8;
typedef __attribute__((ext_vector_type(4))) float  f32x4;

__device__ __forceinline__ f32x4 mfma16(bf16x8 a, bf16x8 b, f32x4 c) {
    return __builtin_amdgcn_mfma_f32_16x16x32_bf16(a, b, c, 0, 0, 0);
}

__device__ __forceinline__ bf16x8 cvt8_f32(const float* p) {
    f32x4 lo = *(const f32x4*)p;
    f32x4 hi = *(const f32x4*)(p + 4);
    bf16x8 r;
    r[0] = (bf16)lo[0]; r[1] = (bf16)lo[1]; r[2] = (bf16)lo[2]; r[3] = (bf16)lo[3];
    r[4] = (bf16)hi[0]; r[5] = (bf16)hi[1]; r[6] = (bf16)hi[2]; r[7] = (bf16)hi[3];
    return r;
}

// async global->LDS, 16 B/lane; LDS dest = wave-uniform base + lane*16 (m104)
__device__ __forceinline__ void gl2lds16(const bf16* g, bf16* l) {
    __builtin_amdgcn_global_load_lds(
        (const __attribute__((address_space(1))) void*)g,
        (__attribute__((address_space(3))) void*)l, 16, 0, 0);
}

// rope 8 consecutive d-elements (4 even/odd pairs) — r9 in-kernel form
// (r13 measured: table-RoPE was neutral-to-negative; trans ops are hidden
// under staging ILP, so in-kernel rope is kept)
__device__ __forceinline__ bf16x8 rope8(bf16x8 v, int tpos, int pair0) {
    bf16x8 r;
    for (int m = 0; m < 4; ++m) {
        int i = pair0 + m;
        float theta = __expf((float)(2 * i) * (-9.210340371976184f / 128.0f));
        float ang   = (float)tpos * theta;
        float sn, cs;
        __sincosf(ang, &sn, &cs);
        float e = (float)v[2 * m], o = (float)v[2 * m + 1];
        r[2 * m]     = (bf16)(e * cs - o * sn);
        r[2 * m + 1] = (bf16)(e * sn + o * cs);
    }
    return r;
}

// ---------------------------------------------------------------------------
__global__ __launch_bounds__(256) void cvt_kernel(const float* __restrict__ src,
                                                  bf16* __restrict__ dst, int n8)
{
    int i = blockIdx.x * 256 + threadIdx.x;
    if (i < n8) *(bf16x8*)(dst + (size_t)i * 8) = cvt8_f32(src + (size_t)i * 8);
}

__global__ __launch_bounds__(256) void cvt_w3(const float* __restrict__ w0,
                                              const float* __restrict__ w1,
                                              const float* __restrict__ w2,
                                              bf16* __restrict__ dst)
{
    int i   = blockIdx.x * 256 + threadIdx.x;     // < 3*2^19
    int sel = i >> 19;
    int off = i & ((1 << 19) - 1);
    const float* s = (sel == 0) ? w0 : (sel == 1) ? w1 : w2;
    *(bf16x8*)(dst + (size_t)i * 8) = cvt8_f32(s + (size_t)off * 8);
}

// ---------------------------------------------------------------------------
// gemm256: C[M,N] = A[M,K] @ B[N,K]^T, bf16 in, OutT out.
// 256x256 tile, BK=64, 512 thr = 8 waves (2Mx4N), per-wave 128x64 output.
// r14 change vs r9 (one variable): DEEPER PREFETCH. r9 staged tile t+1's
// last chunks (c6,c7) in P2 and drained them at P3-end — drain distance
// ~1 phase (~600 cyc) < HBM latency (~900) -> every-tile vmcnt stall with
// all 8 waves blocked. m201's verified schedule keeps 3 half-tiles in
// flight (vmcnt(6)), drain distance >= 2 phases. r14 schedule:
//   P0: reads A0+B01 (12); stage t+1 c4,c5 -> other buf
//   P1: reads B23 (4);     stage t+1 c6,c7 -> other buf
//   P2: reads A1 (8);      no stage
//   P3: stage t+2 c0..c3 -> OWN buf (WAR-safe: own buf's last read is P2,
//       barrier-ordered); MQ; vmcnt(4) — drains t+1 fully (its last stage
//       was P1, 2 phases ago ~1250 cyc > HBM), leaves t+2's 4 in flight.
// Every tile's c0-c3 staged two tiles early, c4-c7 one tile early.
// Phase skeleton (reads | stage | SB0 | bar | lgkm0 | SB0 | 16 MFMA |
// SB0 | bar) is byte-identical to measured r9.
// ---------------------------------------------------------------------------

#define BAR() __builtin_amdgcn_s_barrier()
#define SB0() __builtin_amdgcn_sched_barrier(0)
#define WAIT_LGKM0() asm volatile("s_waitcnt lgkmcnt(0)" ::: "memory")

#define READ_A(BSEL, mh) do {                                                 \
    _Pragma("unroll") for (int ii = 0; ii < 4; ++ii)                          \
    _Pragma("unroll") for (int kk = 0; kk < 2; ++kk)                          \
        Af[ii][kk] = *(const bf16x8*)&As[BSEL][aoff[(mh)*4+ii] + ksw[kk]];    \
    } while (0)

#define READ_B(BSEL, j0) do {                                                 \
    _Pragma("unroll") for (int jj = 0; jj < 2; ++jj)                          \
    _Pragma("unroll") for (int kk = 0; kk < 2; ++kk)                          \
        Bf[(j0)+jj][kk] = *(const bf16x8*)&Bs[BSEL][bof[(j0)+jj] + ksw[kk]];  \
    } while (0)

#define MQ(i0, j0) do {                                                       \
    __builtin_amdgcn_s_setprio(1);                                            \
    _Pragma("unroll") for (int ii = 0; ii < 4; ++ii)                          \
    _Pragma("unroll") for (int jj = 0; jj < 2; ++jj)                          \
    _Pragma("unroll") for (int kk = 0; kk < 2; ++kk)                          \
        acc[(i0)+ii][(j0)+jj] =                                               \
            mfma16(Af[ii][kk], Bf[(j0)+jj][kk], acc[(i0)+ii][(j0)+jj]);       \
    __builtin_amdgcn_s_setprio(0);                                            \
    } while (0)

// stage one 64-row chunk (8 KB) of tile tt into buffer BSEL.
// c in 0..3 -> A rows c*64..; c in 4..7 -> B rows (c-4)*64..
#define STG1(BSEL, tt, c) do {                                                \
    if ((c) < 4)                                                              \
        gl2lds16(Ag + (size_t)(c) * 64 * lda + (size_t)(tt) * 64,             \
                 &As[BSEL][(c) * 4096 + w * 512]);                            \
    else                                                                      \
        gl2lds16(Bg + (size_t)((c) - 4) * 64 * ldb + (size_t)(tt) * 64,       \
                 &Bs[BSEL][((c) - 4) * 4096 + w * 512]);                      \
    } while (0)

// MODE: 0 = steady; 1 = t==NT-2 (stage t+1 c4..c7 only, vmcnt(0));
//       2 = t==NT-1 (tail, nothing)
#define TILE_ITER(BSEL, OSEL, tt, MODE) do {                                  \
    /* ---- P0: A-half0 (8) + B01 (4) reads; stage t+1 c4,c5 ---- */          \
    READ_A(BSEL, 0); READ_B(BSEL, 0);                                         \
    if (MODE < 2) { STG1(OSEL, (tt) + 1, 4); STG1(OSEL, (tt) + 1, 5); }       \
    SB0(); BAR(); WAIT_LGKM0(); SB0();                                        \
    MQ(0, 0);                                                                 \
    SB0(); BAR();                                                             \
    /* ---- P1: B23 (4) reads; stage t+1 c6,c7 ---- */                        \
    READ_B(BSEL, 2);                                                          \
    if (MODE < 2) { STG1(OSEL, (tt) + 1, 6); STG1(OSEL, (tt) + 1, 7); }       \
    SB0(); BAR(); WAIT_LGKM0(); SB0();                                        \
    MQ(0, 2);                                                                 \
    SB0(); BAR();                                                             \
    /* ---- P2: A-half1 (8) reads; no stage ---- */                           \
    READ_A(BSEL, 1);                                                          \
    SB0(); BAR(); WAIT_LGKM0(); SB0();                                        \
    MQ(4, 2);                                                                 \
    SB0(); BAR();                                                             \
    /* ---- P3: stage t+2 c0..c3 into OWN buf; counted vmcnt ---- */          \
    if (MODE == 0) { STG1(BSEL, (tt) + 2, 0); STG1(BSEL, (tt) + 2, 1);        \
                     STG1(BSEL, (tt) + 2, 2); STG1(BSEL, (tt) + 2, 3); }      \
    SB0(); BAR(); SB0();                                                      \
    MQ(4, 0);                                                                 \
    if (MODE == 0) asm volatile("s_waitcnt vmcnt(4)" ::: "memory");           \
    if (MODE == 1) asm volatile("s_waitcnt vmcnt(0)" ::: "memory");           \
    SB0(); BAR(); } while (0)

template<typename OutT>
__global__ __launch_bounds__(512, 2) void gemm256(const bf16* __restrict__ A,
                                                  const bf16* __restrict__ B,
                                                  OutT* __restrict__ C,
                                                  int lda, int ldb, int ldc,
                                                  int K, int gx)
{
    __shared__ __align__(16) bf16 As[2][16384];   // 2 x 32 KB
    __shared__ __align__(16) bf16 Bs[2][16384];   // 2 x 32 KB  (128 KB total)

    const int tid  = threadIdx.x;
    const int w    = tid >> 6;        // wave 0..7
    const int l    = tid & 63;
    const int quad = l >> 4;
    const int ln   = l & 15;
    const int wm   = w >> 2;          // 0..1
    const int wn   = w & 3;           // 0..3

    // T1: chunked XCD swizzle (gridDim.x % 8 == 0 -> bijective)
    const int nwg = gridDim.x;
    const int bid = blockIdx.x;
    const int swz = (bid & 7) * (nwg >> 3) + (bid >> 3);
    const int bx  = swz % gx;
    const int by  = swz / gx;
    const size_t mbase = (size_t)by * 256;
    const size_t nbase = (size_t)bx * 256;

    // staging map: thread t -> row t>>3 (of 64-row chunk), logical 8-elem
    // chunk (t&7)^(row&7)  [pre-swizzled source; linear LDS dest = m104-safe]
    const int srow   = tid >> 3;                  // 0..63
    const int schunk = (tid & 7) ^ (srow & 7);
    const bf16* Ag = A + (mbase + srow) * (size_t)lda + schunk * 8;
    const bf16* Bg = B + (nbase + srow) * (size_t)ldb + schunk * 8;

    // read-side element offsets (xor-swizzled k-chunk)
    const int xr = ln & 7;
    int aoff[8], bof[4], ksw[2];
#pragma unroll
    for (int i = 0; i < 8; ++i) aoff[i] = (wm * 128 + i * 16 + ln) * 64;
#pragma unroll
    for (int j = 0; j < 4; ++j) bof[j]  = (wn * 64  + j * 16 + ln) * 64;
#pragma unroll
    for (int kk = 0; kk < 2; ++kk) ksw[kk] = ((kk * 4 + quad) ^ xr) * 8;

    f32x4 acc[8][4];
#pragma unroll
    for (int i = 0; i < 8; ++i)
#pragma unroll
        for (int j = 0; j < 4; ++j) acc[i][j] = (f32x4){0.f, 0.f, 0.f, 0.f};

    bf16x8 Af[4][2];   // current A half
    bf16x8 Bf[4][2];   // all B frags for current K-tile

    // prologue: tile0 full (8) + tile1 c0..c3 (4); vmcnt(4) drains tile0,
    // leaves tile1's 4 in flight (drained by tile0's P3 vmcnt(4))
    STG1(0, 0, 0); STG1(0, 0, 1); STG1(0, 0, 2); STG1(0, 0, 3);
    STG1(0, 0, 4); STG1(0, 0, 5); STG1(0, 0, 6); STG1(0, 0, 7);
    STG1(1, 1, 0); STG1(1, 1, 1); STG1(1, 1, 2); STG1(1, 1, 3);
    asm volatile("s_waitcnt vmcnt(4)" ::: "memory");   // tile0 landed
    BAR();

    const int NT = K >> 6;            // 32 for K=2048 (even, >=4)
    int t = 0;
#pragma unroll 1
    for (; t < NT - 2; t += 2) {
        TILE_ITER(0, 1, t, 0);
        TILE_ITER(1, 0, t + 1, 0);
    }
    TILE_ITER(0, 1, NT - 2, 1);       // stages tile NT-1 c4..c7, vmcnt(0)
    TILE_ITER(1, 0, NT - 1, 2);       // last tile, nothing outstanding

    // C/D: col = ln, row = quad*4 + r  (m89/m91-verified)
#pragma unroll
    for (int i = 0; i < 8; ++i)
#pragma unroll
        for (int j = 0; j < 4; ++j)
#pragma unroll
            for (int r = 0; r < 4; ++r) {
                size_t row = mbase + wm * 128 + i * 16 + quad * 4 + r;
                size_t col = nbase + wn * 64 + j * 16 + ln;
                C[row * (size_t)ldc + col] = (OutT)acc[i][j][r];
            }
}

#undef BAR
#undef SB0
#undef WAIT_LGKM0
#undef READ_A
#undef READ_B
#undef MQ
#undef STG1
#undef TILE_ITER

// ---------------------------------------------------------------------------
// Attention over fused buffer, RoPE fused in (r9 form — best measured).
// One workgroup per (b,h).
// ---------------------------------------------------------------------------
__global__ __launch_bounds__(256) void attn_kernel(bf16* __restrict__ buf)
{
    __shared__ __align__(16) bf16 KP_lds[128 * 136];  // roped K, then P
    __shared__ __align__(16) bf16 Vt_lds[128 * 136];  // Vt[d][k] = V[k][d]

    const int bh = blockIdx.x;
    const int b  = bh >> 4;
    const int h  = bh & 15;
    const size_t baseQ = (size_t)b * SEQ * LDF + (size_t)h * D_HEAD;
    const size_t baseK = baseQ + KOFF;
    const size_t baseV = baseQ + VOFF;

    const int tid  = threadIdx.x;
    const int w    = tid >> 6;
    const int l    = tid & 63;
    const int quad = l >> 4;
    const int ln   = l & 15;

    // ---- stage roped K rows + V^T: thread -> row k=tid>>1, half d0=(tid&1)*64
    {
        int k  = tid >> 1;
        int d0 = (tid & 1) * 64;
        const bf16* kp = buf + baseK + (size_t)k * LDF + d0;
        const bf16* vp = buf + baseV + (size_t)k * LDF + d0;
        for (int c = 0; c < 8; ++c) {
            bf16x8 kv = *(const bf16x8*)(kp + c * 8);
            *(bf16x8*)&KP_lds[k * 136 + d0 + c * 8] = rope8(kv, k, d0 / 2 + c * 4);
            bf16x8 vv = *(const bf16x8*)(vp + c * 8);
            for (int j = 0; j < 8; ++j)
                Vt_lds[(d0 + c * 8 + j) * 136 + k] = vv[j];
        }
    }
    __syncthreads();

    const float rscale = 0.08838834764831845f;   // 1/sqrt(128)
    const float NEG    = -1e30f;

    // ---- phase 1: S = ropeQ @ ropeK^T for both strips, softmax in regs ----
    f32x4 acc2[2][8];
    for (int s = 0; s < 2; ++s)
        for (int nt = 0; nt < 8; ++nt) acc2[s][nt] = (f32x4){0.f, 0.f, 0.f, 0.f};

    for (int s = 0; s < 2; ++s) {
        const int q0 = w * 32 + s * 16;
        for (int kt = 0; kt < 4; ++kt) {
            bf16x8 qa = *(const bf16x8*)(buf + baseQ + (size_t)(q0 + ln) * LDF
                                           + kt * 32 + quad * 8);
            bf16x8 a = rope8(qa, q0 + ln, kt * 16 + quad * 4);
            for (int nt = 0; nt < 8; ++nt) {
                bf16x8 bb = *(const bf16x8*)&KP_lds[(nt * 16 + ln) * 136
                                                    + kt * 32 + quad * 8];
                acc2[s][nt] = mfma16(a, bb, acc2[s][nt]);
            }
        }

        float mx[4] = {NEG, NEG, NEG, NEG};
        for (int nt = 0; nt < 8; ++nt)
            for (int r = 0; r < 4; ++r) {
                int q = q0 + quad * 4 + r;
                int c = nt * 16 + ln;
                float v = acc2[s][nt][r] * rscale;
                v = (c <= q) ? v : NEG;
                acc2[s][nt][r] = v;
                mx[r] = fmaxf(mx[r], v);
            }
        for (int m = 1; m < 16; m <<= 1)
            for (int r = 0; r < 4; ++r)
                mx[r] = fmaxf(mx[r], __shfl_xor(mx[r], m));

        float sm[4] = {0.f, 0.f, 0.f, 0.f};
        for (int nt = 0; nt < 8; ++nt)
            for (int r = 0; r < 4; ++r) {
                float p = __expf(acc2[s][nt][r] - mx[r]);
                acc2[s][nt][r] = p;
                sm[r] += p;
            }
        for (int m = 1; m < 16; m <<= 1)
            for (int r = 0; r < 4; ++r)
                sm[r] += __shfl_xor(sm[r], m);

        for (int r = 0; r < 4; ++r) sm[r] = 1.0f / sm[r];
        for (int nt = 0; nt < 8; ++nt)
            for (int r = 0; r < 4; ++r)
                acc2[s][nt][r] *= sm[r];
    }

    __syncthreads();   // all K reads from KP_lds complete

    // ---- write P over the K region (own-wave rows only) ----
    for (int s = 0; s < 2; ++s)
        for (int nt = 0; nt < 8; ++nt)
            for (int r = 0; r < 4; ++r) {
                int q = w * 32 + s * 16 + quad * 4 + r;
                int c = nt * 16 + ln;
                KP_lds[q * 136 + c] = (bf16)acc2[s][nt][r];
            }

    // ---- phase 2: O = P @ V ----
    f32x4 o[2][8];
    for (int s = 0; s < 2; ++s)
        for (int nt = 0; nt < 8; ++nt) o[s][nt] = (f32x4){0.f, 0.f, 0.f, 0.f};

    for (int kt = 0; kt < 4; ++kt) {
        bf16x8 a0 = *(const bf16x8*)&KP_lds[(w * 32 +      ln) * 136 + kt * 32 + quad * 8];
        bf16x8 a1 = *(const bf16x8*)&KP_lds[(w * 32 + 16 + ln) * 136 + kt * 32 + quad * 8];
        for (int nt = 0; nt < 8; ++nt) {
            bf16x8 bb = *(const bf16x8*)&Vt_lds[(nt * 16 + ln) * 136 + kt * 32 + quad * 8];
            o[0][nt] = mfma16(a0, bb, o[0][nt]);
            o[1][nt] = mfma16(a1, bb, o[1][nt]);
        }
    }

    for (int s = 0; s < 2; ++s)
        for (int nt = 0; nt < 8; ++nt)
            for (int r = 0; r < 4; ++r) {
                int q = w * 32 + s * 16 + quad * 4 + r;
                int d = nt * 16 + ln;
                buf[baseQ + (size_t)q * LDF + d] = (bf16)o[s][nt][r];
            }
}

// ---------------------------------------------------------------------------
extern "C" void kernel_launch(void* const* d_in, const int* in_sizes, int n_in,
                              void* d_out, int out_size, void* d_ws, size_t ws_size,
                              hipStream_t stream)
{
    const float* x  = (const float*)d_in[0];
    const float* Wq = (const float*)d_in[1];
    const float* Wk = (const float*)d_in[2];
    const float* Wv = (const float*)d_in[3];
    const float* Wo = (const float*)d_in[4];
    float* out = (float*)d_out;

    // ws layout (bf16 elems): QKV 100.7 MB | xb 33.6 MB (WoB reuses) | WB 25.2 MB
    bf16* QKV = (bf16*)d_ws;
    bf16* xb  = QKV + (size_t)BT * LDF;
    bf16* WB  = xb + (size_t)BT * D_MODEL;
    bf16* WoB = xb;                               // free after QKV GEMM

    const int n8x = BT * D_MODEL / 8;             // 2,097,152
    const int n8w = D_MODEL * D_MODEL / 8;        //   524,288 = 2^19

    cvt_kernel<<<(n8x + 255) / 256, 256, 0, stream>>>(x, xb, n8x);
    cvt_w3<<<(3 * n8w) / 256, 256, 0, stream>>>(Wq, Wk, Wv, WB);

    // fused QKV projection: [8192 x 6144] = xb @ WB^T  (768 blocks, %8==0)
    gemm256<bf16><<<dim3((LDF / 256) * (BT / 256)), 512, 0, stream>>>(
        xb, WB, QKV, D_MODEL, D_MODEL, LDF, D_MODEL, LDF / 256);

    cvt_kernel<<<(n8w + 255) / 256, 256, 0, stream>>>(Wo, WoB, n8w);

    // attention with fused RoPE; O in-place over Q columns
    attn_kernel<<<BATCH * N_HEADS, 256, 0, stream>>>(QKV);

    // output projection: out[8192 x 2048] = O @ Wo^T (fp32 out, 256 blocks)
    gemm256<float><<<dim3((D_MODEL / 256) * (BT / 256)), 512, 0, stream>>>(
        QKV, WoB, out, LDF, D_MODEL, D_MODEL, D_MODEL, D_MODEL / 256);
}

// Round 15
// 470.415 us; speedup vs baseline: 1.0278x; 1.0278x over previous
//
#include <hip/hip_runtime.h>
#include <hip/hip_bf16.h>
#include <math.h>

#define D_MODEL 2048
#define N_HEADS 16
#define D_HEAD  128
#define BATCH   64
#define SEQ     128
#define BT      (BATCH*SEQ)   // 8192 rows
#define LDF     6144          // fused QKV row stride
#define KOFF    2048
#define VOFF    4096

typedef __bf16 bf16;
typedef __attribute__((ext_vector_type(8))) __bf16 bf16x8;
typedef __attribute__((ext_vector_type(4))) float  f32x4;

__device__ __forceinline__ f32x4 mfma16(bf16x8 a, bf16x8 b, f32x4 c) {
    return __builtin_amdgcn_mfma_f32_16x16x32_bf16(a, b, c, 0, 0, 0);
}

__device__ __forceinline__ bf16x8 cvt8_f32(const float* p) {
    f32x4 lo = *(const f32x4*)p;
    f32x4 hi = *(const f32x4*)(p + 4);
    bf16x8 r;
    r[0] = (bf16)lo[0]; r[1] = (bf16)lo[1]; r[2] = (bf16)lo[2]; r[3] = (bf16)lo[3];
    r[4] = (bf16)hi[0]; r[5] = (bf16)hi[1]; r[6] = (bf16)hi[2]; r[7] = (bf16)hi[3];
    return r;
}

// async global->LDS, 16 B/lane; LDS dest = wave-uniform base + lane*16 (m104)
__device__ __forceinline__ void gl2lds16(const bf16* g, bf16* l) {
    __builtin_amdgcn_global_load_lds(
        (const __attribute__((address_space(1))) void*)g,
        (__attribute__((address_space(3))) void*)l, 16, 0, 0);
}

// rope 8 consecutive d-elements (4 even/odd pairs) — in-kernel form.
// (r13 measured: table-RoPE regressed; trans ops hide under staging ILP)
__device__ __forceinline__ bf16x8 rope8(bf16x8 v, int tpos, int pair0) {
    bf16x8 r;
    for (int m = 0; m < 4; ++m) {
        int i = pair0 + m;
        float theta = __expf((float)(2 * i) * (-9.210340371976184f / 128.0f));
        float ang   = (float)tpos * theta;
        float sn, cs;
        __sincosf(ang, &sn, &cs);
        float e = (float)v[2 * m], o = (float)v[2 * m + 1];
        r[2 * m]     = (bf16)(e * cs - o * sn);
        r[2 * m + 1] = (bf16)(e * sn + o * cs);
    }
    return r;
}

// ---------------------------------------------------------------------------
__global__ __launch_bounds__(256) void cvt_kernel(const float* __restrict__ src,
                                                  bf16* __restrict__ dst, int n8)
{
    int i = blockIdx.x * 256 + threadIdx.x;
    if (i < n8) *(bf16x8*)(dst + (size_t)i * 8) = cvt8_f32(src + (size_t)i * 8);
}

__global__ __launch_bounds__(256) void cvt_w3(const float* __restrict__ w0,
                                              const float* __restrict__ w1,
                                              const float* __restrict__ w2,
                                              bf16* __restrict__ dst)
{
    int i   = blockIdx.x * 256 + threadIdx.x;     // < 3*2^19
    int sel = i >> 19;
    int off = i & ((1 << 19) - 1);
    const float* s = (sel == 0) ? w0 : (sel == 1) ? w1 : w2;
    *(bf16x8*)(dst + (size_t)i * 8) = cvt8_f32(s + (size_t)off * 8);
}

// ---------------------------------------------------------------------------
// gemm256 — r9 configuration VERBATIM (best measured: QKV 206.5 us,
// MfmaUtil 44.5%, WRITE_SIZE clean). Session evidence: 6 schedule variants
// (r1/r3/r5/r7/r9/r14) — r9 is the local optimum; deeper prefetch (r14,
// -17us regression) and SB0 order-pinning (r7) both hurt. FROZEN.
// 256x256 tile, BK=64, 512 thr = 8 waves (2Mx4N), per-wave 128x64 output.
// 4 phases/K-tile: {ds_reads | 2x stage | SB0 | bar | lgkm0 | SB0 |
// setprio(1) 16 MFMA setprio(0) | [P3: vmcnt(2)] | SB0 | bar}.
// Stage spread: t's P0..P2 stage t+1 c2..c7 -> other buf; P3 stages t+2
// c0,c1 -> own buf. vmcnt(2) once per tile (never 0 in steady state).
// ---------------------------------------------------------------------------

#define BAR() __builtin_amdgcn_s_barrier()
#define SB0() __builtin_amdgcn_sched_barrier(0)
#define WAIT_LGKM0() asm volatile("s_waitcnt lgkmcnt(0)" ::: "memory")

#define READ_A(BSEL, mh) do {                                                 \
    _Pragma("unroll") for (int ii = 0; ii < 4; ++ii)                          \
    _Pragma("unroll") for (int kk = 0; kk < 2; ++kk)                          \
        Af[ii][kk] = *(const bf16x8*)&As[BSEL][aoff[(mh)*4+ii] + ksw[kk]];    \
    } while (0)

#define READ_B(BSEL, j0) do {                                                 \
    _Pragma("unroll") for (int jj = 0; jj < 2; ++jj)                          \
    _Pragma("unroll") for (int kk = 0; kk < 2; ++kk)                          \
        Bf[(j0)+jj][kk] = *(const bf16x8*)&Bs[BSEL][bof[(j0)+jj] + ksw[kk]];  \
    } while (0)

#define MQ(i0, j0) do {                                                       \
    __builtin_amdgcn_s_setprio(1);                                            \
    _Pragma("unroll") for (int ii = 0; ii < 4; ++ii)                          \
    _Pragma("unroll") for (int jj = 0; jj < 2; ++jj)                          \
    _Pragma("unroll") for (int kk = 0; kk < 2; ++kk)                          \
        acc[(i0)+ii][(j0)+jj] =                                               \
            mfma16(Af[ii][kk], Bf[(j0)+jj][kk], acc[(i0)+ii][(j0)+jj]);       \
    __builtin_amdgcn_s_setprio(0);                                            \
    } while (0)

// stage one 64-row chunk (8 KB) of tile tt into buffer BSEL.
// c in 0..3 -> A rows c*64..; c in 4..7 -> B rows (c-4)*64..
#define STG1(BSEL, tt, c) do {                                                \
    if ((c) < 4)                                                              \
        gl2lds16(Ag + (size_t)(c) * 64 * lda + (size_t)(tt) * 64,             \
                 &As[BSEL][(c) * 4096 + w * 512]);                            \
    else                                                                      \
        gl2lds16(Bg + (size_t)((c) - 4) * 64 * ldb + (size_t)(tt) * 64,       \
                 &Bs[BSEL][((c) - 4) * 4096 + w * 512]);                      \
    } while (0)

// MODE: 0 = steady; 1 = pre-tail (stage t+1 only, vmcnt(0)); 2 = tail (none)
#define TILE_ITER(BSEL, OSEL, tt, MODE) do {                                  \
    /* ---- P0: A-half0 (8) + B01 (4) reads; stage t+1 c2,c3 ---- */          \
    READ_A(BSEL, 0); READ_B(BSEL, 0);                                         \
    if (MODE < 2) { STG1(OSEL, (tt) + 1, 2); STG1(OSEL, (tt) + 1, 3); }       \
    SB0(); BAR(); WAIT_LGKM0(); SB0();                                        \
    MQ(0, 0);                                                                 \
    SB0(); BAR();                                                             \
    /* ---- P1: B23 (4) reads; stage t+1 c4,c5 ---- */                        \
    READ_B(BSEL, 2);                                                          \
    if (MODE < 2) { STG1(OSEL, (tt) + 1, 4); STG1(OSEL, (tt) + 1, 5); }       \
    SB0(); BAR(); WAIT_LGKM0(); SB0();                                        \
    MQ(0, 2);                                                                 \
    SB0(); BAR();                                                             \
    /* ---- P2: A-half1 (8) reads; stage t+1 c6,c7 ---- */                    \
    READ_A(BSEL, 1);                                                          \
    if (MODE < 2) { STG1(OSEL, (tt) + 1, 6); STG1(OSEL, (tt) + 1, 7); }       \
    SB0(); BAR(); WAIT_LGKM0(); SB0();                                        \
    MQ(4, 2);                                                                 \
    SB0(); BAR();                                                             \
    /* ---- P3: no reads; stage t+2 c0,c1 into own buf; counted vmcnt ---- */ \
    if (MODE == 0) { STG1(BSEL, (tt) + 2, 0); STG1(BSEL, (tt) + 2, 1); }      \
    SB0(); BAR(); SB0();                                                      \
    MQ(4, 0);                                                                 \
    if (MODE == 0) asm volatile("s_waitcnt vmcnt(2)" ::: "memory");           \
    if (MODE == 1) asm volatile("s_waitcnt vmcnt(0)" ::: "memory");           \
    SB0(); BAR(); } while (0)

template<typename OutT>
__global__ __launch_bounds__(512, 2) void gemm256(const bf16* __restrict__ A,
                                                  const bf16* __restrict__ B,
                                                  OutT* __restrict__ C,
                                                  int lda, int ldb, int ldc,
                                                  int K, int gx)
{
    __shared__ __align__(16) bf16 As[2][16384];   // 2 x 32 KB
    __shared__ __align__(16) bf16 Bs[2][16384];   // 2 x 32 KB  (128 KB total)

    const int tid  = threadIdx.x;
    const int w    = tid >> 6;        // wave 0..7
    const int l    = tid & 63;
    const int quad = l >> 4;
    const int ln   = l & 15;
    const int wm   = w >> 2;          // 0..1
    const int wn   = w & 3;           // 0..3

    // T1: chunked XCD swizzle (gridDim.x % 8 == 0 -> bijective)
    const int nwg = gridDim.x;
    const int bid = blockIdx.x;
    const int swz = (bid & 7) * (nwg >> 3) + (bid >> 3);
    const int bx  = swz % gx;
    const int by  = swz / gx;
    const size_t mbase = (size_t)by * 256;
    const size_t nbase = (size_t)bx * 256;

    // staging map: thread t -> row t>>3 (of 64-row chunk), logical 8-elem
    // chunk (t&7)^(row&7)  [pre-swizzled source; linear LDS dest = m104-safe]
    const int srow   = tid >> 3;                  // 0..63
    const int schunk = (tid & 7) ^ (srow & 7);
    const bf16* Ag = A + (mbase + srow) * (size_t)lda + schunk * 8;
    const bf16* Bg = B + (nbase + srow) * (size_t)ldb + schunk * 8;

    // read-side element offsets (xor-swizzled k-chunk)
    const int xr = ln & 7;
    int aoff[8], bof[4], ksw[2];
#pragma unroll
    for (int i = 0; i < 8; ++i) aoff[i] = (wm * 128 + i * 16 + ln) * 64;
#pragma unroll
    for (int j = 0; j < 4; ++j) bof[j]  = (wn * 64  + j * 16 + ln) * 64;
#pragma unroll
    for (int kk = 0; kk < 2; ++kk) ksw[kk] = ((kk * 4 + quad) ^ xr) * 8;

    f32x4 acc[8][4];
#pragma unroll
    for (int i = 0; i < 8; ++i)
#pragma unroll
        for (int j = 0; j < 4; ++j) acc[i][j] = (f32x4){0.f, 0.f, 0.f, 0.f};

    bf16x8 Af[4][2];   // current A half
    bf16x8 Bf[4][2];   // all B frags for current K-tile

    // prologue: tile0 full burst + tile1 chunks 0,1  (10 calls in flight)
    STG1(0, 0, 0); STG1(0, 0, 1); STG1(0, 0, 2); STG1(0, 0, 3);
    STG1(0, 0, 4); STG1(0, 0, 5); STG1(0, 0, 6); STG1(0, 0, 7);
    STG1(1, 1, 0); STG1(1, 1, 1);
    asm volatile("s_waitcnt vmcnt(2)" ::: "memory");   // tile0 landed
    BAR();

    const int NT = K >> 6;            // 32 for K=2048 (even, >=4)
    int t = 0;
#pragma unroll 1
    for (; t < NT - 2; t += 2) {
        TILE_ITER(0, 1, t, 0);
        TILE_ITER(1, 0, t + 1, 0);
    }
    TILE_ITER(0, 1, NT - 2, 1);       // stages tile NT-1 tail chunks, vmcnt(0)
    TILE_ITER(1, 0, NT - 1, 2);       // last tile, nothing outstanding

    // C/D: col = ln, row = quad*4 + r  (m89/m91-verified)
#pragma unroll
    for (int i = 0; i < 8; ++i)
#pragma unroll
        for (int j = 0; j < 4; ++j)
#pragma unroll
            for (int r = 0; r < 4; ++r) {
                size_t row = mbase + wm * 128 + i * 16 + quad * 4 + r;
                size_t col = nbase + wn * 64 + j * 16 + ln;
                C[row * (size_t)ldc + col] = (OutT)acc[i][j][r];
            }
}

#undef BAR
#undef SB0
#undef WAIT_LGKM0
#undef READ_A
#undef READ_B
#undef MQ
#undef STG1
#undef TILE_ITER

// ---------------------------------------------------------------------------
// Attention over fused buffer, RoPE fused in (r9 form — best measured).
// One workgroup per (b,h).
// ---------------------------------------------------------------------------
__global__ __launch_bounds__(256) void attn_kernel(bf16* __restrict__ buf)
{
    __shared__ __align__(16) bf16 KP_lds[128 * 136];  // roped K, then P
    __shared__ __align__(16) bf16 Vt_lds[128 * 136];  // Vt[d][k] = V[k][d]

    const int bh = blockIdx.x;
    const int b  = bh >> 4;
    const int h  = bh & 15;
    const size_t baseQ = (size_t)b * SEQ * LDF + (size_t)h * D_HEAD;
    const size_t baseK = baseQ + KOFF;
    const size_t baseV = baseQ + VOFF;

    const int tid  = threadIdx.x;
    const int w    = tid >> 6;
    const int l    = tid & 63;
    const int quad = l >> 4;
    const int ln   = l & 15;

    // ---- stage roped K rows + V^T: thread -> row k=tid>>1, half d0=(tid&1)*64
    {
        int k  = tid >> 1;
        int d0 = (tid & 1) * 64;
        const bf16* kp = buf + baseK + (size_t)k * LDF + d0;
        const bf16* vp = buf + baseV + (size_t)k * LDF + d0;
        for (int c = 0; c < 8; ++c) {
            bf16x8 kv = *(const bf16x8*)(kp + c * 8);
            *(bf16x8*)&KP_lds[k * 136 + d0 + c * 8] = rope8(kv, k, d0 / 2 + c * 4);
            bf16x8 vv = *(const bf16x8*)(vp + c * 8);
            for (int j = 0; j < 8; ++j)
                Vt_lds[(d0 + c * 8 + j) * 136 + k] = vv[j];
        }
    }
    __syncthreads();

    const float rscale = 0.08838834764831845f;   // 1/sqrt(128)
    const float NEG    = -1e30f;

    // ---- phase 1: S = ropeQ @ ropeK^T for both strips, softmax in regs ----
    f32x4 acc2[2][8];
    for (int s = 0; s < 2; ++s)
        for (int nt = 0; nt < 8; ++nt) acc2[s][nt] = (f32x4){0.f, 0.f, 0.f, 0.f};

    for (int s = 0; s < 2; ++s) {
        const int q0 = w * 32 + s * 16;
        for (int kt = 0; kt < 4; ++kt) {
            bf16x8 qa = *(const bf16x8*)(buf + baseQ + (size_t)(q0 + ln) * LDF
                                           + kt * 32 + quad * 8);
            bf16x8 a = rope8(qa, q0 + ln, kt * 16 + quad * 4);
            for (int nt = 0; nt < 8; ++nt) {
                bf16x8 bb = *(const bf16x8*)&KP_lds[(nt * 16 + ln) * 136
                                                    + kt * 32 + quad * 8];
                acc2[s][nt] = mfma16(a, bb, acc2[s][nt]);
            }
        }

        float mx[4] = {NEG, NEG, NEG, NEG};
        for (int nt = 0; nt < 8; ++nt)
            for (int r = 0; r < 4; ++r) {
                int q = q0 + quad * 4 + r;
                int c = nt * 16 + ln;
                float v = acc2[s][nt][r] * rscale;
                v = (c <= q) ? v : NEG;
                acc2[s][nt][r] = v;
                mx[r] = fmaxf(mx[r], v);
            }
        for (int m = 1; m < 16; m <<= 1)
            for (int r = 0; r < 4; ++r)
                mx[r] = fmaxf(mx[r], __shfl_xor(mx[r], m));

        float sm[4] = {0.f, 0.f, 0.f, 0.f};
        for (int nt = 0; nt < 8; ++nt)
            for (int r = 0; r < 4; ++r) {
                float p = __expf(acc2[s][nt][r] - mx[r]);
                acc2[s][nt][r] = p;
                sm[r] += p;
            }
        for (int m = 1; m < 16; m <<= 1)
            for (int r = 0; r < 4; ++r)
                sm[r] += __shfl_xor(sm[r], m);

        for (int r = 0; r < 4; ++r) sm[r] = 1.0f / sm[r];
        for (int nt = 0; nt < 8; ++nt)
            for (int r = 0; r < 4; ++r)
                acc2[s][nt][r] *= sm[r];
    }

    __syncthreads();   // all K reads from KP_lds complete

    // ---- write P over the K region (own-wave rows only) ----
    for (int s = 0; s < 2; ++s)
        for (int nt = 0; nt < 8; ++nt)
            for (int r = 0; r < 4; ++r) {
                int q = w * 32 + s * 16 + quad * 4 + r;
                int c = nt * 16 + ln;
                KP_lds[q * 136 + c] = (bf16)acc2[s][nt][r];
            }

    // ---- phase 2: O = P @ V ----
    f32x4 o[2][8];
    for (int s = 0; s < 2; ++s)
        for (int nt = 0; nt < 8; ++nt) o[s][nt] = (f32x4){0.f, 0.f, 0.f, 0.f};

    for (int kt = 0; kt < 4; ++kt) {
        bf16x8 a0 = *(const bf16x8*)&KP_lds[(w * 32 +      ln) * 136 + kt * 32 + quad * 8];
        bf16x8 a1 = *(const bf16x8*)&KP_lds[(w * 32 + 16 + ln) * 136 + kt * 32 + quad * 8];
        for (int nt = 0; nt < 8; ++nt) {
            bf16x8 bb = *(const bf16x8*)&Vt_lds[(nt * 16 + ln) * 136 + kt * 32 + quad * 8];
            o[0][nt] = mfma16(a0, bb, o[0][nt]);
            o[1][nt] = mfma16(a1, bb, o[1][nt]);
        }
    }

    for (int s = 0; s < 2; ++s)
        for (int nt = 0; nt < 8; ++nt)
            for (int r = 0; r < 4; ++r) {
                int q = w * 32 + s * 16 + quad * 4 + r;
                int d = nt * 16 + ln;
                buf[baseQ + (size_t)q * LDF + d] = (bf16)o[s][nt][r];
            }
}

// ---------------------------------------------------------------------------
extern "C" void kernel_launch(void* const* d_in, const int* in_sizes, int n_in,
                              void* d_out, int out_size, void* d_ws, size_t ws_size,
                              hipStream_t stream)
{
    const float* x  = (const float*)d_in[0];
    const float* Wq = (const float*)d_in[1];
    const float* Wk = (const float*)d_in[2];
    const float* Wv = (const float*)d_in[3];
    const float* Wo = (const float*)d_in[4];
    float* out = (float*)d_out;

    // ws layout (bf16 elems): QKV 100.7 MB | xb 33.6 MB (WoB reuses) | WB 25.2 MB
    bf16* QKV = (bf16*)d_ws;
    bf16* xb  = QKV + (size_t)BT * LDF;
    bf16* WB  = xb + (size_t)BT * D_MODEL;
    bf16* WoB = xb;                               // free after QKV GEMM

    const int n8x = BT * D_MODEL / 8;             // 2,097,152
    const int n8w = D_MODEL * D_MODEL / 8;        //   524,288 = 2^19

    cvt_kernel<<<(n8x + 255) / 256, 256, 0, stream>>>(x, xb, n8x);
    cvt_w3<<<(3 * n8w) / 256, 256, 0, stream>>>(Wq, Wk, Wv, WB);

    // fused QKV projection: [8192 x 6144] = xb @ WB^T  (768 blocks, %8==0)
    gemm256<bf16><<<dim3((LDF / 256) * (BT / 256)), 512, 0, stream>>>(
        xb, WB, QKV, D_MODEL, D_MODEL, LDF, D_MODEL, LDF / 256);

    cvt_kernel<<<(n8w + 255) / 256, 256, 0, stream>>>(Wo, WoB, n8w);

    // attention with fused RoPE; O in-place over Q columns
    attn_kernel<<<BATCH * N_HEADS, 256, 0, stream>>>(QKV);

    // output projection: out[8192 x 2048] = O @ Wo^T (fp32 out, 256 blocks)
    gemm256<float><<<dim3((D_MODEL / 256) * (BT / 256)), 512, 0, stream>>>(
        QKV, WoB, out, LDF, D_MODEL, D_MODEL, D_MODEL, D_MODEL / 256);
}

// Round 16
// 467.720 us; speedup vs baseline: 1.0338x; 1.0058x over previous
//
#include <hip/hip_runtime.h>
#include <hip/hip_bf16.h>
#include <math.h>

#define D_MODEL 2048
#define N_HEADS 16
#define D_HEAD  128
#define BATCH   64
#define SEQ     128
#define BT      (BATCH*SEQ)   // 8192 rows
#define LDF     6144          // fused QKV row stride
#define KOFF    2048
#define VOFF    4096

typedef __bf16 bf16;
typedef __attribute__((ext_vector_type(8))) __bf16 bf16x8;
typedef __attribute__((ext_vector_type(4))) float  f32x4;

__device__ __forceinline__ f32x4 mfma16(bf16x8 a, bf16x8 b, f32x4 c) {
    return __builtin_amdgcn_mfma_f32_16x16x32_bf16(a, b, c, 0, 0, 0);
}

__device__ __forceinline__ bf16x8 cvt8_f32(const float* p) {
    f32x4 lo = *(const f32x4*)p;
    f32x4 hi = *(const f32x4*)(p + 4);
    bf16x8 r;
    r[0] = (bf16)lo[0]; r[1] = (bf16)lo[1]; r[2] = (bf16)lo[2]; r[3] = (bf16)lo[3];
    r[4] = (bf16)hi[0]; r[5] = (bf16)hi[1]; r[6] = (bf16)hi[2]; r[7] = (bf16)hi[3];
    return r;
}

// async global->LDS, 16 B/lane; LDS dest = wave-uniform base + lane*16 (m104)
__device__ __forceinline__ void gl2lds16(const bf16* g, bf16* l) {
    __builtin_amdgcn_global_load_lds(
        (const __attribute__((address_space(1))) void*)g,
        (__attribute__((address_space(3))) void*)l, 16, 0, 0);
}

// rope 8 consecutive d-elements (4 even/odd pairs) — in-kernel form.
// (r13 measured: table-RoPE regressed; trans ops hide under staging ILP)
__device__ __forceinline__ bf16x8 rope8(bf16x8 v, int tpos, int pair0) {
    bf16x8 r;
    for (int m = 0; m < 4; ++m) {
        int i = pair0 + m;
        float theta = __expf((float)(2 * i) * (-9.210340371976184f / 128.0f));
        float ang   = (float)tpos * theta;
        float sn, cs;
        __sincosf(ang, &sn, &cs);
        float e = (float)v[2 * m], o = (float)v[2 * m + 1];
        r[2 * m]     = (bf16)(e * cs - o * sn);
        r[2 * m + 1] = (bf16)(e * sn + o * cs);
    }
    return r;
}

// ---------------------------------------------------------------------------
// r16: consolidated fp32->bf16 conversion. One launch handles x (n8x chunks)
// + nsel weight matrices (2^19 chunks each; sel 0..2 -> WB contiguous,
// sel 3 -> WoB). 6 launches -> 4 when workspace has 8.4 MB slack for WoB.
// ---------------------------------------------------------------------------
__global__ __launch_bounds__(256) void cvt_all(const float* __restrict__ x,
                                               const float* __restrict__ w0,
                                               const float* __restrict__ w1,
                                               const float* __restrict__ w2,
                                               const float* __restrict__ w3,
                                               bf16* __restrict__ xb,
                                               bf16* __restrict__ WB,
                                               bf16* __restrict__ WoB,
                                               int n8x, int nsel)
{
    int i = blockIdx.x * 256 + threadIdx.x;
    if (i < n8x) {
        *(bf16x8*)(xb + (size_t)i * 8) = cvt8_f32(x + (size_t)i * 8);
        return;
    }
    int j   = i - n8x;                         // < nsel * 2^19
    int sel = j >> 19;
    if (sel >= nsel) return;
    int off = j & ((1 << 19) - 1);
    const float* s = (sel == 0) ? w0 : (sel == 1) ? w1 : (sel == 2) ? w2 : w3;
    bf16* d = (sel < 3) ? (WB + (size_t)j * 8) : (WoB + (size_t)off * 8);
    *(bf16x8*)d = cvt8_f32(s + (size_t)off * 8);
}

// fallback single-src convert (used for Wo when no ws slack; r9 path)
__global__ __launch_bounds__(256) void cvt_kernel(const float* __restrict__ src,
                                                  bf16* __restrict__ dst, int n8)
{
    int i = blockIdx.x * 256 + threadIdx.x;
    if (i < n8) *(bf16x8*)(dst + (size_t)i * 8) = cvt8_f32(src + (size_t)i * 8);
}

// ---------------------------------------------------------------------------
// gemm256 — r9 configuration VERBATIM (best measured: QKV ~205 us,
// MfmaUtil 44.5%, WRITE_SIZE clean; reproduced r15). Session evidence:
// 6 schedule variants (r1/r3/r5/r7/r9/r14) — r9 is the local optimum.
// FROZEN. 256x256 tile, BK=64, 512 thr = 8 waves (2Mx4N).
// 4 phases/K-tile: {ds_reads | 2x stage | SB0 | bar | lgkm0 | SB0 |
// setprio(1) 16 MFMA setprio(0) | [P3: vmcnt(2)] | SB0 | bar}.
// ---------------------------------------------------------------------------

#define BAR() __builtin_amdgcn_s_barrier()
#define SB0() __builtin_amdgcn_sched_barrier(0)
#define WAIT_LGKM0() asm volatile("s_waitcnt lgkmcnt(0)" ::: "memory")

#define READ_A(BSEL, mh) do {                                                 \
    _Pragma("unroll") for (int ii = 0; ii < 4; ++ii)                          \
    _Pragma("unroll") for (int kk = 0; kk < 2; ++kk)                          \
        Af[ii][kk] = *(const bf16x8*)&As[BSEL][aoff[(mh)*4+ii] + ksw[kk]];    \
    } while (0)

#define READ_B(BSEL, j0) do {                                                 \
    _Pragma("unroll") for (int jj = 0; jj < 2; ++jj)                          \
    _Pragma("unroll") for (int kk = 0; kk < 2; ++kk)                          \
        Bf[(j0)+jj][kk] = *(const bf16x8*)&Bs[BSEL][bof[(j0)+jj] + ksw[kk]];  \
    } while (0)

#define MQ(i0, j0) do {                                                       \
    __builtin_amdgcn_s_setprio(1);                                            \
    _Pragma("unroll") for (int ii = 0; ii < 4; ++ii)                          \
    _Pragma("unroll") for (int jj = 0; jj < 2; ++jj)                          \
    _Pragma("unroll") for (int kk = 0; kk < 2; ++kk)                          \
        acc[(i0)+ii][(j0)+jj] =                                               \
            mfma16(Af[ii][kk], Bf[(j0)+jj][kk], acc[(i0)+ii][(j0)+jj]);       \
    __builtin_amdgcn_s_setprio(0);                                            \
    } while (0)

// stage one 64-row chunk (8 KB) of tile tt into buffer BSEL.
// c in 0..3 -> A rows c*64..; c in 4..7 -> B rows (c-4)*64..
#define STG1(BSEL, tt, c) do {                                                \
    if ((c) < 4)                                                              \
        gl2lds16(Ag + (size_t)(c) * 64 * lda + (size_t)(tt) * 64,             \
                 &As[BSEL][(c) * 4096 + w * 512]);                            \
    else                                                                      \
        gl2lds16(Bg + (size_t)((c) - 4) * 64 * ldb + (size_t)(tt) * 64,       \
                 &Bs[BSEL][((c) - 4) * 4096 + w * 512]);                      \
    } while (0)

// MODE: 0 = steady; 1 = pre-tail (stage t+1 only, vmcnt(0)); 2 = tail (none)
#define TILE_ITER(BSEL, OSEL, tt, MODE) do {                                  \
    /* ---- P0: A-half0 (8) + B01 (4) reads; stage t+1 c2,c3 ---- */          \
    READ_A(BSEL, 0); READ_B(BSEL, 0);                                         \
    if (MODE < 2) { STG1(OSEL, (tt) + 1, 2); STG1(OSEL, (tt) + 1, 3); }       \
    SB0(); BAR(); WAIT_LGKM0(); SB0();                                        \
    MQ(0, 0);                                                                 \
    SB0(); BAR();                                                             \
    /* ---- P1: B23 (4) reads; stage t+1 c4,c5 ---- */                        \
    READ_B(BSEL, 2);                                                          \
    if (MODE < 2) { STG1(OSEL, (tt) + 1, 4); STG1(OSEL, (tt) + 1, 5); }       \
    SB0(); BAR(); WAIT_LGKM0(); SB0();                                        \
    MQ(0, 2);                                                                 \
    SB0(); BAR();                                                             \
    /* ---- P2: A-half1 (8) reads; stage t+1 c6,c7 ---- */                    \
    READ_A(BSEL, 1);                                                          \
    if (MODE < 2) { STG1(OSEL, (tt) + 1, 6); STG1(OSEL, (tt) + 1, 7); }       \
    SB0(); BAR(); WAIT_LGKM0(); SB0();                                        \
    MQ(4, 2);                                                                 \
    SB0(); BAR();                                                             \
    /* ---- P3: no reads; stage t+2 c0,c1 into own buf; counted vmcnt ---- */ \
    if (MODE == 0) { STG1(BSEL, (tt) + 2, 0); STG1(BSEL, (tt) + 2, 1); }      \
    SB0(); BAR(); SB0();                                                      \
    MQ(4, 0);                                                                 \
    if (MODE == 0) asm volatile("s_waitcnt vmcnt(2)" ::: "memory");           \
    if (MODE == 1) asm volatile("s_waitcnt vmcnt(0)" ::: "memory");           \
    SB0(); BAR(); } while (0)

template<typename OutT>
__global__ __launch_bounds__(512, 2) void gemm256(const bf16* __restrict__ A,
                                                  const bf16* __restrict__ B,
                                                  OutT* __restrict__ C,
                                                  int lda, int ldb, int ldc,
                                                  int K, int gx)
{
    __shared__ __align__(16) bf16 As[2][16384];   // 2 x 32 KB
    __shared__ __align__(16) bf16 Bs[2][16384];   // 2 x 32 KB  (128 KB total)

    const int tid  = threadIdx.x;
    const int w    = tid >> 6;        // wave 0..7
    const int l    = tid & 63;
    const int quad = l >> 4;
    const int ln   = l & 15;
    const int wm   = w >> 2;          // 0..1
    const int wn   = w & 3;           // 0..3

    // T1: chunked XCD swizzle (gridDim.x % 8 == 0 -> bijective)
    const int nwg = gridDim.x;
    const int bid = blockIdx.x;
    const int swz = (bid & 7) * (nwg >> 3) + (bid >> 3);
    const int bx  = swz % gx;
    const int by  = swz / gx;
    const size_t mbase = (size_t)by * 256;
    const size_t nbase = (size_t)bx * 256;

    // staging map: thread t -> row t>>3 (of 64-row chunk), logical 8-elem
    // chunk (t&7)^(row&7)  [pre-swizzled source; linear LDS dest = m104-safe]
    const int srow   = tid >> 3;                  // 0..63
    const int schunk = (tid & 7) ^ (srow & 7);
    const bf16* Ag = A + (mbase + srow) * (size_t)lda + schunk * 8;
    const bf16* Bg = B + (nbase + srow) * (size_t)ldb + schunk * 8;

    // read-side element offsets (xor-swizzled k-chunk)
    const int xr = ln & 7;
    int aoff[8], bof[4], ksw[2];
#pragma unroll
    for (int i = 0; i < 8; ++i) aoff[i] = (wm * 128 + i * 16 + ln) * 64;
#pragma unroll
    for (int j = 0; j < 4; ++j) bof[j]  = (wn * 64  + j * 16 + ln) * 64;
#pragma unroll
    for (int kk = 0; kk < 2; ++kk) ksw[kk] = ((kk * 4 + quad) ^ xr) * 8;

    f32x4 acc[8][4];
#pragma unroll
    for (int i = 0; i < 8; ++i)
#pragma unroll
        for (int j = 0; j < 4; ++j) acc[i][j] = (f32x4){0.f, 0.f, 0.f, 0.f};

    bf16x8 Af[4][2];   // current A half
    bf16x8 Bf[4][2];   // all B frags for current K-tile

    // prologue: tile0 full burst + tile1 chunks 0,1  (10 calls in flight)
    STG1(0, 0, 0); STG1(0, 0, 1); STG1(0, 0, 2); STG1(0, 0, 3);
    STG1(0, 0, 4); STG1(0, 0, 5); STG1(0, 0, 6); STG1(0, 0, 7);
    STG1(1, 1, 0); STG1(1, 1, 1);
    asm volatile("s_waitcnt vmcnt(2)" ::: "memory");   // tile0 landed
    BAR();

    const int NT = K >> 6;            // 32 for K=2048 (even, >=4)
    int t = 0;
#pragma unroll 1
    for (; t < NT - 2; t += 2) {
        TILE_ITER(0, 1, t, 0);
        TILE_ITER(1, 0, t + 1, 0);
    }
    TILE_ITER(0, 1, NT - 2, 1);       // stages tile NT-1 tail chunks, vmcnt(0)
    TILE_ITER(1, 0, NT - 1, 2);       // last tile, nothing outstanding

    // C/D: col = ln, row = quad*4 + r  (m89/m91-verified)
#pragma unroll
    for (int i = 0; i < 8; ++i)
#pragma unroll
        for (int j = 0; j < 4; ++j)
#pragma unroll
            for (int r = 0; r < 4; ++r) {
                size_t row = mbase + wm * 128 + i * 16 + quad * 4 + r;
                size_t col = nbase + wn * 64 + j * 16 + ln;
                C[row * (size_t)ldc + col] = (OutT)acc[i][j][r];
            }
}

#undef BAR
#undef SB0
#undef WAIT_LGKM0
#undef READ_A
#undef READ_B
#undef MQ
#undef STG1
#undef TILE_ITER

// ---------------------------------------------------------------------------
// Attention over fused buffer, RoPE fused in (r9 form — best measured).
// One workgroup per (b,h).
// ---------------------------------------------------------------------------
__global__ __launch_bounds__(256) void attn_kernel(bf16* __restrict__ buf)
{
    __shared__ __align__(16) bf16 KP_lds[128 * 136];  // roped K, then P
    __shared__ __align__(16) bf16 Vt_lds[128 * 136];  // Vt[d][k] = V[k][d]

    const int bh = blockIdx.x;
    const int b  = bh >> 4;
    const int h  = bh & 15;
    const size_t baseQ = (size_t)b * SEQ * LDF + (size_t)h * D_HEAD;
    const size_t baseK = baseQ + KOFF;
    const size_t baseV = baseQ + VOFF;

    const int tid  = threadIdx.x;
    const int w    = tid >> 6;
    const int l    = tid & 63;
    const int quad = l >> 4;
    const int ln   = l & 15;

    // ---- stage roped K rows + V^T: thread -> row k=tid>>1, half d0=(tid&1)*64
    {
        int k  = tid >> 1;
        int d0 = (tid & 1) * 64;
        const bf16* kp = buf + baseK + (size_t)k * LDF + d0;
        const bf16* vp = buf + baseV + (size_t)k * LDF + d0;
        for (int c = 0; c < 8; ++c) {
            bf16x8 kv = *(const bf16x8*)(kp + c * 8);
            *(bf16x8*)&KP_lds[k * 136 + d0 + c * 8] = rope8(kv, k, d0 / 2 + c * 4);
            bf16x8 vv = *(const bf16x8*)(vp + c * 8);
            for (int j = 0; j < 8; ++j)
                Vt_lds[(d0 + c * 8 + j) * 136 + k] = vv[j];
        }
    }
    __syncthreads();

    const float rscale = 0.08838834764831845f;   // 1/sqrt(128)
    const float NEG    = -1e30f;

    // ---- phase 1: S = ropeQ @ ropeK^T for both strips, softmax in regs ----
    f32x4 acc2[2][8];
    for (int s = 0; s < 2; ++s)
        for (int nt = 0; nt < 8; ++nt) acc2[s][nt] = (f32x4){0.f, 0.f, 0.f, 0.f};

    for (int s = 0; s < 2; ++s) {
        const int q0 = w * 32 + s * 16;
        for (int kt = 0; kt < 4; ++kt) {
            bf16x8 qa = *(const bf16x8*)(buf + baseQ + (size_t)(q0 + ln) * LDF
                                           + kt * 32 + quad * 8);
            bf16x8 a = rope8(qa, q0 + ln, kt * 16 + quad * 4);
            for (int nt = 0; nt < 8; ++nt) {
                bf16x8 bb = *(const bf16x8*)&KP_lds[(nt * 16 + ln) * 136
                                                    + kt * 32 + quad * 8];
                acc2[s][nt] = mfma16(a, bb, acc2[s][nt]);
            }
        }

        float mx[4] = {NEG, NEG, NEG, NEG};
        for (int nt = 0; nt < 8; ++nt)
            for (int r = 0; r < 4; ++r) {
                int q = q0 + quad * 4 + r;
                int c = nt * 16 + ln;
                float v = acc2[s][nt][r] * rscale;
                v = (c <= q) ? v : NEG;
                acc2[s][nt][r] = v;
                mx[r] = fmaxf(mx[r], v);
            }
        for (int m = 1; m < 16; m <<= 1)
            for (int r = 0; r < 4; ++r)
                mx[r] = fmaxf(mx[r], __shfl_xor(mx[r], m));

        float sm[4] = {0.f, 0.f, 0.f, 0.f};
        for (int nt = 0; nt < 8; ++nt)
            for (int r = 0; r < 4; ++r) {
                float p = __expf(acc2[s][nt][r] - mx[r]);
                acc2[s][nt][r] = p;
                sm[r] += p;
            }
        for (int m = 1; m < 16; m <<= 1)
            for (int r = 0; r < 4; ++r)
                sm[r] += __shfl_xor(sm[r], m);

        for (int r = 0; r < 4; ++r) sm[r] = 1.0f / sm[r];
        for (int nt = 0; nt < 8; ++nt)
            for (int r = 0; r < 4; ++r)
                acc2[s][nt][r] *= sm[r];
    }

    __syncthreads();   // all K reads from KP_lds complete

    // ---- write P over the K region (own-wave rows only) ----
    for (int s = 0; s < 2; ++s)
        for (int nt = 0; nt < 8; ++nt)
            for (int r = 0; r < 4; ++r) {
                int q = w * 32 + s * 16 + quad * 4 + r;
                int c = nt * 16 + ln;
                KP_lds[q * 136 + c] = (bf16)acc2[s][nt][r];
            }

    // ---- phase 2: O = P @ V ----
    f32x4 o[2][8];
    for (int s = 0; s < 2; ++s)
        for (int nt = 0; nt < 8; ++nt) o[s][nt] = (f32x4){0.f, 0.f, 0.f, 0.f};

    for (int kt = 0; kt < 4; ++kt) {
        bf16x8 a0 = *(const bf16x8*)&KP_lds[(w * 32 +      ln) * 136 + kt * 32 + quad * 8];
        bf16x8 a1 = *(const bf16x8*)&KP_lds[(w * 32 + 16 + ln) * 136 + kt * 32 + quad * 8];
        for (int nt = 0; nt < 8; ++nt) {
            bf16x8 bb = *(const bf16x8*)&Vt_lds[(nt * 16 + ln) * 136 + kt * 32 + quad * 8];
            o[0][nt] = mfma16(a0, bb, o[0][nt]);
            o[1][nt] = mfma16(a1, bb, o[1][nt]);
        }
    }

    for (int s = 0; s < 2; ++s)
        for (int nt = 0; nt < 8; ++nt)
            for (int r = 0; r < 4; ++r) {
                int q = w * 32 + s * 16 + quad * 4 + r;
                int d = nt * 16 + ln;
                buf[baseQ + (size_t)q * LDF + d] = (bf16)o[s][nt][r];
            }
}

// ---------------------------------------------------------------------------
extern "C" void kernel_launch(void* const* d_in, const int* in_sizes, int n_in,
                              void* d_out, int out_size, void* d_ws, size_t ws_size,
                              hipStream_t stream)
{
    const float* x  = (const float*)d_in[0];
    const float* Wq = (const float*)d_in[1];
    const float* Wk = (const float*)d_in[2];
    const float* Wv = (const float*)d_in[3];
    const float* Wo = (const float*)d_in[4];
    float* out = (float*)d_out;

    // ws layout (bf16 elems): QKV 100.7 MB | xb 33.6 MB | WB 25.2 MB |
    //                         [WoB 8.4 MB if slack, else WoB aliases xb]
    bf16* QKV = (bf16*)d_ws;
    bf16* xb  = QKV + (size_t)BT * LDF;
    bf16* WB  = xb + (size_t)BT * D_MODEL;

    const size_t baseElems = (size_t)BT * LDF + (size_t)BT * D_MODEL
                           + (size_t)3 * D_MODEL * D_MODEL;
    const size_t needElems = baseElems + (size_t)D_MODEL * D_MODEL;
    const bool   slack     = ws_size >= needElems * sizeof(bf16);

    bf16* WoB = slack ? (WB + (size_t)3 * D_MODEL * D_MODEL) : xb;

    const int n8x  = BT * D_MODEL / 8;            // 2,097,152
    const int n8w  = D_MODEL * D_MODEL / 8;       //   524,288 = 2^19
    const int nsel = slack ? 4 : 3;

    // one consolidated conversion launch (x + 3 or 4 weight matrices)
    cvt_all<<<(n8x + nsel * n8w + 255) / 256, 256, 0, stream>>>(
        x, Wq, Wk, Wv, Wo, xb, WB, WoB, n8x, nsel);

    // fused QKV projection: [8192 x 6144] = xb @ WB^T  (768 blocks, %8==0)
    gemm256<bf16><<<dim3((LDF / 256) * (BT / 256)), 512, 0, stream>>>(
        xb, WB, QKV, D_MODEL, D_MODEL, LDF, D_MODEL, LDF / 256);

    // no-slack fallback: convert Wo into xb (free after QKV GEMM), r9 path
    if (!slack)
        cvt_kernel<<<(n8w + 255) / 256, 256, 0, stream>>>(Wo, WoB, n8w);

    // attention with fused RoPE; O in-place over Q columns
    attn_kernel<<<BATCH * N_HEADS, 256, 0, stream>>>(QKV);

    // output projection: out[8192 x 2048] = O @ Wo^T (fp32 out, 256 blocks)
    gemm256<float><<<dim3((D_MODEL / 256) * (BT / 256)), 512, 0, stream>>>(
        QKV, WoB, out, LDF, D_MODEL, D_MODEL, D_MODEL, D_MODEL / 256);
}